// Round 14
// baseline (59.449 us; speedup 1.0000x reference)
//
#include <hip/hip_runtime.h>
#include <math.h>

#define ROWS 32
#define LROW 15104
#define TWIN 128
#define NWIN 118
#define TRIM 14848              // LROW - 2*TWIN
#define NW   (ROWS * NWIN)      // 3776 real windows
#define WPB  16                 // windows per block (2 per wave)
#define BPR  8                  // 8*16 = 128 >= 118 (10 masked)
#define NBLK (ROWS * BPR)       // 256 = 8 * 32 (bijective XCD chunks, 1/CU)
#define YSEG 768                // per-wave LDS floats: two 384-float windows

// Raw (unscaled) correlation sums for one window.
// Fully unrolled: unroll depth IS the latency hiding (R8/R9 lesson).
// x via VMEM (lz trick) so it never mixes with the ds_read lgkmcnt stream (R11).
__device__ __forceinline__ void window_corr(
        const float* __restrict__ xw,
        const float* __restrict__ yw,
        int lane, int lz,
        float c[4], float sy[4], float& sx_l, float& part_l) {
    {
        float xa = xw[lane], xb = xw[lane + 64];
        float ya = yw[256 + lane], yb = yw[320 + lane];
        float d0 = xa - ya, d1 = xb - yb;
        part_l = d0 * d0 + d1 * d1;
        sx_l   = xa * xa + xb * xb;
    }

    const float4* ys4 = (const float4*)yw;

    float4 yv0 = ys4[lane];
    float yf0 = yv0.x, yf1 = yv0.y, yf2 = yv0.z;
    float c0 = 0.f, c1 = 0.f, c2 = 0.f, c3 = 0.f;
    float q = 0.f;

    #pragma unroll
    for (int kb = 0; kb < 32; ++kb) {
        float4 xv  = *(const float4*)(xw + 4 * kb + lz);  // VMEM broadcast
        float4 yv1 = ys4[lane + kb + 1];                  // the only LDS read
        c0 += xv.x*yv0.x + xv.y*yv0.y + xv.z*yv0.z + xv.w*yv0.w;
        c1 += xv.x*yv0.y + xv.y*yv0.z + xv.z*yv0.w + xv.w*yv1.x;
        c2 += xv.x*yv0.z + xv.y*yv0.w + xv.z*yv1.x + xv.w*yv1.y;
        c3 += xv.x*yv0.w + xv.y*yv1.x + xv.z*yv1.y + xv.w*yv1.z;
        q  += yv0.x*yv0.x + yv0.y*yv0.y + yv0.z*yv0.z + yv0.w*yv0.w;
        yv0 = yv1;
    }
    c[0] = c0; c[1] = c1; c[2] = c2; c[3] = c3;
    sy[0] = q;
    sy[1] = sy[0] - yf0*yf0 + yv0.x*yv0.x;
    sy[2] = sy[1] - yf1*yf1 + yv0.y*yv0.y;
    sy[3] = sy[2] - yf2*yf2 + yv0.z*yv0.z;
}

// stage one 384-float y window (96 float4) into a per-wave LDS segment.
// In-wave dependency only -> no __syncthreads needed before own reads.
__device__ __forceinline__ void stage_window(
        const float* __restrict__ rrow, int n, float* __restrict__ seg,
        int lane) {
    int base = (n - 1) * TWIN;           // may be negative (zero pad)
    {
        int g = base + 4 * lane;
        float4 v = make_float4(0.f, 0.f, 0.f, 0.f);
        if (g >= 0 && g < LROW) v = *(const float4*)(rrow + g);
        *(float4*)&seg[4 * lane] = v;
    }
    if (lane < 32) {
        int g = base + 4 * (lane + 64);
        float4 v = make_float4(0.f, 0.f, 0.f, 0.f);
        if (g >= 0 && g < LROW) v = *(const float4*)(rrow + g);
        *(float4*)&seg[4 * (lane + 64)] = v;
    }
}

// -------- fused: per-wave staged corr + overlapped stats, 1 barrier --------
__global__ __launch_bounds__(512) void loss_fused(
        const float* __restrict__ data,
        const float* __restrict__ target,
        float* __restrict__ blocksums) {
    // XCD-chunked swizzle: 32 consecutive logical blocks (= 4 rows) per XCD.
    int b0 = blockIdx.x;
    int b  = (b0 & 7) * (NBLK / 8) + (b0 >> 3);
    int row = b / BPR;
    int n0  = (b % BPR) * WPB;
    int tid  = threadIdx.x;
    int wave = tid >> 6;
    int lane = tid & 63;

    // runtime 0 in a VGPR, opaque to uniformity analysis
    int lz;
    asm volatile("v_mov_b32 %0, 0" : "=v"(lz));

    __shared__ float  ys[8][YSEG];      // per-wave private segments (24 KB)
    __shared__ float4 wsum[8];
    __shared__ float  wl[8];

    const float* xrow = data   + row * LROW;
    const float* rrow = target + row * LROW;

    int  nA     = n0 + wave;
    int  nB     = n0 + 8 + wave;
    bool validA = (nA < NWIN);
    bool validB = (nB < NWIN);
    int  nuA    = __builtin_amdgcn_readfirstlane(validA ? nA : NWIN - 1);
    int  nuB    = __builtin_amdgcn_readfirstlane(validB ? nB : NWIN - 1);

    // ---- Phase 1: stage own two y windows (no barrier needed) ----
    float* segA = &ys[wave][0];
    float* segB = &ys[wave][384];
    stage_window(rrow, nuA, segA, lane);
    stage_window(rrow, nuB, segB, lane);

    // ---- Phase 2: correlation on own segments (starts immediately) ----
    float cA[4], syA[4], sxA, partA;
    float cB[4], syB[4], sxB, partB;
    window_corr(xrow + nuA * TWIN, segA, lane, lz, cA, syA, sxA, partA);
    window_corr(xrow + nuB * TWIN, segB, lane, lz, cB, syB, sxB, partB);

    // joint 4-value reduce tree (one 6-level pass for both windows)
    #pragma unroll
    for (int off = 32; off > 0; off >>= 1) {
        sxA   += __shfl_xor(sxA,   off, 64);
        partA += __shfl_xor(partA, off, 64);
        sxB   += __shfl_xor(sxB,   off, 64);
        partB += __shfl_xor(partB, off, 64);
    }

    // ---- Phase 3: stats scan AFTER corr (overlaps other waves' corr) ----
    {
        const float4* x4 = (const float4*)(xrow + TWIN);
        const float4* r4 = (const float4*)(rrow + TWIN);
        float sd = 0.f, sd2 = 0.f, sr = 0.f, sr2 = 0.f;
        for (int i = tid; i < TRIM / 4; i += 512) {
            float4 a = x4[i], bv = r4[i];
            sd  += a.x + a.y + a.z + a.w;
            sd2 += a.x*a.x + a.y*a.y + a.z*a.z + a.w*a.w;
            sr  += bv.x + bv.y + bv.z + bv.w;
            sr2 += bv.x*bv.x + bv.y*bv.y + bv.z*bv.z + bv.w*bv.w;
        }
        #pragma unroll
        for (int off = 32; off > 0; off >>= 1) {
            sd  += __shfl_xor(sd,  off, 64);
            sd2 += __shfl_xor(sd2, off, 64);
            sr  += __shfl_xor(sr,  off, 64);
            sr2 += __shfl_xor(sr2, off, 64);
        }
        if (lane == 0) wsum[wave] = make_float4(sd, sd2, sr, sr2);
    }
    __syncthreads();    // the ONLY pre-epilogue barrier

    // ---- Phase 4: combine wsum -> scale^2 (every thread, no extra barrier) --
    float scale2;
    {
        float td = 0.f, td2 = 0.f, tr = 0.f, tr2 = 0.f;
        #pragma unroll
        for (int i = 0; i < 8; ++i) {
            float4 p = wsum[i];
            td += p.x; td2 += p.y; tr += p.z; tr2 += p.w;
        }
        const float inv = 1.0f / (float)TRIM;
        float md = td * inv, mr = tr * inv;
        float vx = fmaxf(td2 * inv - md * md, 0.f);
        float vr = fmaxf(tr2 * inv - mr * mr, 0.f);
        float mag_x = sqrtf(vx), mag_r = sqrtf(vr);
        float mag_min = fminf(mag_x, mag_r);
        float scale = 1.0f / (sqrtf(mag_min * mag_r) + 0.001f);
        scale2 = scale * scale;
    }

    // ---- Phase 5: epilogue ----
    const float inv = 1.0f / (float)TWIN;
    int   s0  = lane * 4;
    float wp[4];
    #pragma unroll
    for (int j = 0; j < 4; ++j) {
        float ph = (float)(s0 + j) * (float)(M_PI / 128.0);
        float cp = __cosf(ph);
        float bw = 0.42f - 0.5f*cp + 0.08f*(2.f*cp*cp - 1.f);
        wp[j] = 100.f * (1.f - bw) + 1.f;            // (w + 1)
    }

    float lminA = 1e30f, lminB = 1e30f;
    #pragma unroll
    for (int j = 0; j < 4; ++j) {
        float mA = scale2 * (sxA - 2.f*cA[j] + syA[j]) * inv;
        float mB = scale2 * (sxB - 2.f*cB[j] + syB[j]) * inv;
        lminA = fminf(lminA, (mA + 1.f) * wp[j] - 1.f);
        lminB = fminf(lminB, (mB + 1.f) * wp[j] - 1.f);
    }
    // s = 256: w[256] = 100 exactly
    lminA = fminf(lminA, (scale2 * partA * inv + 1.f) * 101.f - 1.f);
    lminB = fminf(lminB, (scale2 * partB * inv + 1.f) * 101.f - 1.f);

    #pragma unroll
    for (int off = 32; off > 0; off >>= 1) {
        lminA = fminf(lminA, __shfl_xor(lminA, off, 64));
        lminB = fminf(lminB, __shfl_xor(lminB, off, 64));
    }

    float wsum_loss = (validA ? lminA : 0.f) + (validB ? lminB : 0.f);

    if (lane == 0) wl[wave] = wsum_loss;
    __syncthreads();
    if (tid == 0) {
        float s = 0.f;
        #pragma unroll
        for (int i = 0; i < 8; ++i) s += wl[i];   // fixed order: deterministic
        blocksums[b] = s;
    }
}

// ---------------- final mean ----------------
__global__ __launch_bounds__(256) void finish_kernel(
        const float* __restrict__ blocksums,
        float* __restrict__ out) {
    int tid = threadIdx.x;
    float s = 0.f;
    for (int i = tid; i < NBLK; i += 256) s += blocksums[i];
    __shared__ float sh[256];
    sh[tid] = s;
    __syncthreads();
    for (int off = 128; off > 0; off >>= 1) {
        if (tid < off) sh[tid] += sh[tid + off];
        __syncthreads();
    }
    if (tid == 0) out[0] = sh[0] / (float)NW;
}

extern "C" void kernel_launch(void* const* d_in, const int* in_sizes, int n_in,
                              void* d_out, int out_size, void* d_ws, size_t ws_size,
                              hipStream_t stream) {
    const float* data   = (const float*)d_in[0];
    const float* target = (const float*)d_in[1];
    float* blocksums = (float*)d_ws;

    loss_fused<<<NBLK, 512, 0, stream>>>(data, target, blocksums);
    finish_kernel<<<1, 256, 0, stream>>>(blocksums, (float*)d_out);
}

// Round 15
// 18.745 us; speedup vs baseline: 3.1714x; 3.1714x over previous
//
#include <hip/hip_runtime.h>
#include <math.h>

#define ROWS 32
#define LROW 15104
#define TWIN 128
#define NWIN 118
#define TRIM 14848              // LROW - 2*TWIN
#define NW   (ROWS * NWIN)      // 3776 real windows
#define WPB  16                 // windows per block (2 per wave)
#define BPR  8                  // 8*16 = 128 >= 118 (10 masked)
#define NBLK (ROWS * BPR)       // 256 = 8 * 32 (bijective XCD chunks, 1/CU)
#define YPAN ((WPB + 2) * TWIN) // 2304 floats: [(n0-1)*128, (n0+17)*128)

// Raw (unscaled) correlation sums for one window.
// Fully unrolled (R8/R9: unroll depth IS the latency hiding).
// x via VMEM lz-trick (R11: keeps s_load off the ds_read lgkmcnt stream).
// float2 accumulators to coax v_pk_fma_f32 (CDNA4 packed fp32, 2 FMA/instr).
__device__ __forceinline__ void window_corr(
        const float* __restrict__ xw,
        const float* __restrict__ yw,
        int lane, int lz,
        float c[4], float sy[4], float& sx_l, float& part_l) {
    {
        float xa = xw[lane], xb = xw[lane + 64];
        float ya = yw[256 + lane], yb = yw[320 + lane];
        float d0 = xa - ya, d1 = xb - yb;
        part_l = d0 * d0 + d1 * d1;
        sx_l   = xa * xa + xb * xb;
    }

    const float4* ys4 = (const float4*)yw;

    float4 yv0 = ys4[lane];
    float yf0 = yv0.x, yf1 = yv0.y, yf2 = yv0.z;
    float2 c01 = make_float2(0.f, 0.f);
    float2 c23 = make_float2(0.f, 0.f);
    float2 q2  = make_float2(0.f, 0.f);

    #pragma unroll
    for (int kb = 0; kb < 32; ++kb) {
        float4 xv  = *(const float4*)(xw + 4 * kb + lz);  // VMEM broadcast
        float4 yv1 = ys4[lane + kb + 1];                  // the only LDS read
        // packed pairs: lane0 -> shift s0+0/s0+2, lane1 -> s0+1/s0+3
        c01 += make_float2(xv.x, xv.x) * make_float2(yv0.x, yv0.y);
        c01 += make_float2(xv.y, xv.y) * make_float2(yv0.y, yv0.z);
        c01 += make_float2(xv.z, xv.z) * make_float2(yv0.z, yv0.w);
        c01 += make_float2(xv.w, xv.w) * make_float2(yv0.w, yv1.x);
        c23 += make_float2(xv.x, xv.x) * make_float2(yv0.z, yv0.w);
        c23 += make_float2(xv.y, xv.y) * make_float2(yv0.w, yv1.x);
        c23 += make_float2(xv.z, xv.z) * make_float2(yv1.x, yv1.y);
        c23 += make_float2(xv.w, xv.w) * make_float2(yv1.y, yv1.z);
        q2  += make_float2(yv0.x, yv0.y) * make_float2(yv0.x, yv0.y);
        q2  += make_float2(yv0.z, yv0.w) * make_float2(yv0.z, yv0.w);
        yv0 = yv1;
    }
    c[0] = c01.x; c[1] = c01.y; c[2] = c23.x; c[3] = c23.y;
    // yv0 = y[s0+128 .. s0+131]
    sy[0] = q2.x + q2.y;
    sy[1] = sy[0] - yf0*yf0 + yv0.x*yv0.x;
    sy[2] = sy[1] - yf1*yf1 + yv0.y*yv0.y;
    sy[3] = sy[2] - yf2*yf2 + yv0.z*yv0.z;
}

// -------- fused: row stats + shifted-L2, 16 windows/block (2 per wave) --------
__global__ __launch_bounds__(512) void loss_fused(
        const float* __restrict__ data,
        const float* __restrict__ target,
        float* __restrict__ blocksums) {
    // XCD-chunked swizzle: 32 consecutive logical blocks (= 4 rows) per XCD.
    int b0 = blockIdx.x;
    int b  = (b0 & 7) * (NBLK / 8) + (b0 >> 3);
    int row = b / BPR;
    int n0  = (b % BPR) * WPB;
    int tid  = threadIdx.x;
    int wave = tid >> 6;
    int lane = tid & 63;

    // runtime 0 in a VGPR, opaque to uniformity analysis
    int lz;
    asm volatile("v_mov_b32 %0, 0" : "=v"(lz));

    __shared__ float  ys[YPAN];
    __shared__ float4 wsum[8];
    __shared__ float  wl[8];

    const float* xrow = data   + row * LROW;
    const float* rrow = target + row * LROW;

    // ---- Phase 1: stats partial sums (all 8 waves share the row scan) ----
    float sd = 0.f, sd2 = 0.f, sr = 0.f, sr2 = 0.f;
    {
        const float4* x4 = (const float4*)(xrow + TWIN);
        const float4* r4 = (const float4*)(rrow + TWIN);
        for (int i = tid; i < TRIM / 4; i += 512) {
            float4 a = x4[i], bv = r4[i];
            sd  += a.x + a.y + a.z + a.w;
            sd2 += a.x*a.x + a.y*a.y + a.z*a.z + a.w*a.w;
            sr  += bv.x + bv.y + bv.z + bv.w;
            sr2 += bv.x*bv.x + bv.y*bv.y + bv.z*bv.z + bv.w*bv.w;
        }
        #pragma unroll
        for (int off = 32; off > 0; off >>= 1) {
            sd  += __shfl_xor(sd,  off, 64);
            sd2 += __shfl_xor(sd2, off, 64);
            sr  += __shfl_xor(sr,  off, 64);
            sr2 += __shfl_xor(sr2, off, 64);
        }
        if (lane == 0) wsum[wave] = make_float4(sd, sd2, sr, sr2);
    }

    // ---- Phase 2: stage UNSCALED y panel ----
    for (int j = tid; j < YPAN / 4; j += 512) {
        int g = (n0 - 1) * TWIN + 4 * j;
        float4 v = make_float4(0.f, 0.f, 0.f, 0.f);
        if (g >= 0 && g < LROW) v = *(const float4*)(rrow + g);
        *(float4*)&ys[4 * j] = v;
    }
    __syncthreads();    // ys + wsum visible

    // ---- Phase 3: every thread combines wsum -> scale^2 (no 2nd barrier) ----
    float scale2;
    {
        float td = 0.f, td2 = 0.f, tr = 0.f, tr2 = 0.f;
        #pragma unroll
        for (int i = 0; i < 8; ++i) {
            float4 p = wsum[i];
            td += p.x; td2 += p.y; tr += p.z; tr2 += p.w;
        }
        const float inv = 1.0f / (float)TRIM;
        float md = td * inv, mr = tr * inv;
        float vx = fmaxf(td2 * inv - md * md, 0.f);
        float vr = fmaxf(tr2 * inv - mr * mr, 0.f);
        float mag_x = sqrtf(vx), mag_r = sqrtf(vr);
        float mag_min = fminf(mag_x, mag_r);
        float scale = 1.0f / (sqrtf(mag_min * mag_r) + 0.001f);
        scale2 = scale * scale;
    }

    // ---- Phase 4: each wave computes windows n0+wave and n0+8+wave ----
    int  nA     = n0 + wave;
    int  nB     = n0 + 8 + wave;
    bool validA = (nA < NWIN);
    bool validB = (nB < NWIN);
    int  nuA    = __builtin_amdgcn_readfirstlane(validA ? nA : NWIN - 1);
    int  nuB    = __builtin_amdgcn_readfirstlane(validB ? nB : NWIN - 1);

    float cA[4], syA[4], sxA, partA;
    float cB[4], syB[4], sxB, partB;
    window_corr(xrow + nuA * TWIN, ys + wave * TWIN,       lane, lz,
                cA, syA, sxA, partA);
    window_corr(xrow + nuB * TWIN, ys + (wave + 8) * TWIN, lane, lz,
                cB, syB, sxB, partB);

    // joint 4-value reduce tree (one 6-level pass for both windows)
    #pragma unroll
    for (int off = 32; off > 0; off >>= 1) {
        sxA   += __shfl_xor(sxA,   off, 64);
        partA += __shfl_xor(partA, off, 64);
        sxB   += __shfl_xor(sxB,   off, 64);
        partB += __shfl_xor(partB, off, 64);
    }

    // Blackman weights: s0 depends only on lane -> compute once per wave
    const float inv = 1.0f / (float)TWIN;
    int   s0  = lane * 4;
    float wp[4];
    #pragma unroll
    for (int j = 0; j < 4; ++j) {
        float ph = (float)(s0 + j) * (float)(M_PI / 128.0);
        float cp = __cosf(ph);
        float bw = 0.42f - 0.5f*cp + 0.08f*(2.f*cp*cp - 1.f);
        wp[j] = 100.f * (1.f - bw) + 1.f;            // (w + 1)
    }

    float lminA = 1e30f, lminB = 1e30f;
    #pragma unroll
    for (int j = 0; j < 4; ++j) {
        float mA = scale2 * (sxA - 2.f*cA[j] + syA[j]) * inv;
        float mB = scale2 * (sxB - 2.f*cB[j] + syB[j]) * inv;
        lminA = fminf(lminA, (mA + 1.f) * wp[j] - 1.f);
        lminB = fminf(lminB, (mB + 1.f) * wp[j] - 1.f);
    }
    // s = 256: w[256] = 100 exactly
    lminA = fminf(lminA, (scale2 * partA * inv + 1.f) * 101.f - 1.f);
    lminB = fminf(lminB, (scale2 * partB * inv + 1.f) * 101.f - 1.f);

    // joint min tree
    #pragma unroll
    for (int off = 32; off > 0; off >>= 1) {
        lminA = fminf(lminA, __shfl_xor(lminA, off, 64));
        lminB = fminf(lminB, __shfl_xor(lminB, off, 64));
    }

    float wsum_loss = (validA ? lminA : 0.f) + (validB ? lminB : 0.f);

    if (lane == 0) wl[wave] = wsum_loss;
    __syncthreads();
    if (tid == 0) {
        float s = 0.f;
        #pragma unroll
        for (int i = 0; i < 8; ++i) s += wl[i];   // fixed order: deterministic
        blocksums[b] = s;
    }
}

// ---------------- final mean ----------------
__global__ __launch_bounds__(256) void finish_kernel(
        const float* __restrict__ blocksums,
        float* __restrict__ out) {
    int tid = threadIdx.x;
    float s = 0.f;
    for (int i = tid; i < NBLK; i += 256) s += blocksums[i];
    __shared__ float sh[256];
    sh[tid] = s;
    __syncthreads();
    for (int off = 128; off > 0; off >>= 1) {
        if (tid < off) sh[tid] += sh[tid + off];
        __syncthreads();
    }
    if (tid == 0) out[0] = sh[0] / (float)NW;
}

extern "C" void kernel_launch(void* const* d_in, const int* in_sizes, int n_in,
                              void* d_out, int out_size, void* d_ws, size_t ws_size,
                              hipStream_t stream) {
    const float* data   = (const float*)d_in[0];
    const float* target = (const float*)d_in[1];
    float* blocksums = (float*)d_ws;

    loss_fused<<<NBLK, 512, 0, stream>>>(data, target, blocksums);
    finish_kernel<<<1, 256, 0, stream>>>(blocksums, (float*)d_out);
}

// Round 16
// 15.896 us; speedup vs baseline: 3.7399x; 1.1792x over previous
//
#include <hip/hip_runtime.h>
#include <math.h>

#define ROWS 32
#define LROW 15104
#define TWIN 128
#define NWIN 118
#define TRIM 14848              // LROW - 2*TWIN
#define NW   (ROWS * NWIN)      // 3776 real windows
#define WPB  16                 // windows per block (2 per wave)
#define BPR  8                  // 8*16 = 128 >= 118 (10 masked)
#define NBLK (ROWS * BPR)       // 256 = 8 * 32 (bijective XCD chunks, 1/CU)
#define YPAN ((WPB + 2) * TWIN) // 2304 floats: [(n0-1)*128, (n0+17)*128)

// Raw (unscaled) correlation sums for one window.
// xw: wave-uniform global ptr to the 128 x taps (VMEM via lz).
// yw: LDS view of 384 y floats.
// Outputs: c[4] cross terms for shifts s0..s0+3, sy[4] window y-energy,
//          sx_l / part_l = per-lane partials (NOT reduced).
// Fully unrolled: unroll depth IS the latency hiding (R8/R9 lesson).
// Scalar FMAs: R15 showed float2 packing regresses (operands not pair-aligned).
__device__ __forceinline__ void window_corr(
        const float* __restrict__ xw,
        const float* __restrict__ yw,
        int lane, int lz,
        float c[4], float sy[4], float& sx_l, float& part_l) {
    {
        float xa = xw[lane], xb = xw[lane + 64];
        float ya = yw[256 + lane], yb = yw[320 + lane];
        float d0 = xa - ya, d1 = xb - yb;
        part_l = d0 * d0 + d1 * d1;
        sx_l   = xa * xa + xb * xb;
    }

    const float4* ys4 = (const float4*)yw;

    float4 yv0 = ys4[lane];
    float yf0 = yv0.x, yf1 = yv0.y, yf2 = yv0.z;
    float c0 = 0.f, c1 = 0.f, c2 = 0.f, c3 = 0.f;
    float q = 0.f;

    #pragma unroll
    for (int kb = 0; kb < 32; ++kb) {
        // x broadcast via VMEM (vmcnt): per-lane equal addresses, L1-resident
        float4 xv  = *(const float4*)(xw + 4 * kb + lz);
        float4 yv1 = ys4[lane + kb + 1];             // the only LDS read
        c0 += xv.x*yv0.x + xv.y*yv0.y + xv.z*yv0.z + xv.w*yv0.w;
        c1 += xv.x*yv0.y + xv.y*yv0.z + xv.z*yv0.w + xv.w*yv1.x;
        c2 += xv.x*yv0.z + xv.y*yv0.w + xv.z*yv1.x + xv.w*yv1.y;
        c3 += xv.x*yv0.w + xv.y*yv1.x + xv.z*yv1.y + xv.w*yv1.z;
        q  += yv0.x*yv0.x + yv0.y*yv0.y + yv0.z*yv0.z + yv0.w*yv0.w;
        yv0 = yv1;
    }
    c[0] = c0; c[1] = c1; c[2] = c2; c[3] = c3;
    // yv0 = y[s0+128 .. s0+131]
    sy[0] = q;
    sy[1] = sy[0] - yf0*yf0 + yv0.x*yv0.x;
    sy[2] = sy[1] - yf1*yf1 + yv0.y*yv0.y;
    sy[3] = sy[2] - yf2*yf2 + yv0.z*yv0.z;
}

// -------- fused: row stats + shifted-L2, 16 windows/block (2 per wave) --------
__global__ __launch_bounds__(512) void loss_fused(
        const float* __restrict__ data,
        const float* __restrict__ target,
        float* __restrict__ blocksums) {
    // XCD-chunked swizzle: 32 consecutive logical blocks (= 4 rows) per XCD.
    int b0 = blockIdx.x;
    int b  = (b0 & 7) * (NBLK / 8) + (b0 >> 3);
    int row = b / BPR;
    int n0  = (b % BPR) * WPB;
    int tid  = threadIdx.x;
    int wave = tid >> 6;
    int lane = tid & 63;

    // runtime 0 in a VGPR, opaque to uniformity analysis
    int lz;
    asm volatile("v_mov_b32 %0, 0" : "=v"(lz));

    __shared__ float  ys[YPAN];
    __shared__ float4 wsum[8];
    __shared__ float  wl[8];

    const float* xrow = data   + row * LROW;
    const float* rrow = target + row * LROW;

    // ---- Phase 1: stats partial sums (all 8 waves share the row scan) ----
    float sd = 0.f, sd2 = 0.f, sr = 0.f, sr2 = 0.f;
    {
        const float4* x4 = (const float4*)(xrow + TWIN);
        const float4* r4 = (const float4*)(rrow + TWIN);
        for (int i = tid; i < TRIM / 4; i += 512) {
            float4 a = x4[i], bv = r4[i];
            sd  += a.x + a.y + a.z + a.w;
            sd2 += a.x*a.x + a.y*a.y + a.z*a.z + a.w*a.w;
            sr  += bv.x + bv.y + bv.z + bv.w;
            sr2 += bv.x*bv.x + bv.y*bv.y + bv.z*bv.z + bv.w*bv.w;
        }
        #pragma unroll
        for (int off = 32; off > 0; off >>= 1) {
            sd  += __shfl_xor(sd,  off, 64);
            sd2 += __shfl_xor(sd2, off, 64);
            sr  += __shfl_xor(sr,  off, 64);
            sr2 += __shfl_xor(sr2, off, 64);
        }
        if (lane == 0) wsum[wave] = make_float4(sd, sd2, sr, sr2);
    }

    // ---- Phase 2: stage UNSCALED y panel ----
    for (int j = tid; j < YPAN / 4; j += 512) {
        int g = (n0 - 1) * TWIN + 4 * j;
        float4 v = make_float4(0.f, 0.f, 0.f, 0.f);
        if (g >= 0 && g < LROW) v = *(const float4*)(rrow + g);
        *(float4*)&ys[4 * j] = v;
    }
    __syncthreads();    // ys + wsum visible

    // ---- Phase 3: every thread combines wsum -> scale^2 (no 2nd barrier) ----
    float scale2;
    {
        float td = 0.f, td2 = 0.f, tr = 0.f, tr2 = 0.f;
        #pragma unroll
        for (int i = 0; i < 8; ++i) {
            float4 p = wsum[i];
            td += p.x; td2 += p.y; tr += p.z; tr2 += p.w;
        }
        const float inv = 1.0f / (float)TRIM;
        float md = td * inv, mr = tr * inv;
        float vx = fmaxf(td2 * inv - md * md, 0.f);
        float vr = fmaxf(tr2 * inv - mr * mr, 0.f);
        float mag_x = sqrtf(vx), mag_r = sqrtf(vr);
        float mag_min = fminf(mag_x, mag_r);
        float scale = 1.0f / (sqrtf(mag_min * mag_r) + 0.001f);
        scale2 = scale * scale;
    }

    // ---- Phase 4: each wave computes windows n0+wave and n0+8+wave ----
    // NO sched_barrier between the two (R11 lesson).
    int  nA     = n0 + wave;
    int  nB     = n0 + 8 + wave;
    bool validA = (nA < NWIN);
    bool validB = (nB < NWIN);
    int  nuA    = __builtin_amdgcn_readfirstlane(validA ? nA : NWIN - 1);
    int  nuB    = __builtin_amdgcn_readfirstlane(validB ? nB : NWIN - 1);

    float cA[4], syA[4], sxA, partA;
    float cB[4], syB[4], sxB, partB;
    window_corr(xrow + nuA * TWIN, ys + wave * TWIN,       lane, lz,
                cA, syA, sxA, partA);
    window_corr(xrow + nuB * TWIN, ys + (wave + 8) * TWIN, lane, lz,
                cB, syB, sxB, partB);

    // joint 4-value reduce tree (one 6-level pass for both windows)
    #pragma unroll
    for (int off = 32; off > 0; off >>= 1) {
        sxA   += __shfl_xor(sxA,   off, 64);
        partA += __shfl_xor(partA, off, 64);
        sxB   += __shfl_xor(sxB,   off, 64);
        partB += __shfl_xor(partB, off, 64);
    }

    // Blackman weights: s0 depends only on lane -> compute once per wave
    const float inv = 1.0f / (float)TWIN;
    int   s0  = lane * 4;
    float wp[4];
    #pragma unroll
    for (int j = 0; j < 4; ++j) {
        float ph = (float)(s0 + j) * (float)(M_PI / 128.0);
        float cp = __cosf(ph);
        float bw = 0.42f - 0.5f*cp + 0.08f*(2.f*cp*cp - 1.f);
        wp[j] = 100.f * (1.f - bw) + 1.f;            // (w + 1)
    }

    float lminA = 1e30f, lminB = 1e30f;
    #pragma unroll
    for (int j = 0; j < 4; ++j) {
        float mA = scale2 * (sxA - 2.f*cA[j] + syA[j]) * inv;
        float mB = scale2 * (sxB - 2.f*cB[j] + syB[j]) * inv;
        lminA = fminf(lminA, (mA + 1.f) * wp[j] - 1.f);
        lminB = fminf(lminB, (mB + 1.f) * wp[j] - 1.f);
    }
    // s = 256: w[256] = 100 exactly
    lminA = fminf(lminA, (scale2 * partA * inv + 1.f) * 101.f - 1.f);
    lminB = fminf(lminB, (scale2 * partB * inv + 1.f) * 101.f - 1.f);

    // joint min tree
    #pragma unroll
    for (int off = 32; off > 0; off >>= 1) {
        lminA = fminf(lminA, __shfl_xor(lminA, off, 64));
        lminB = fminf(lminB, __shfl_xor(lminB, off, 64));
    }

    float wsum_loss = (validA ? lminA : 0.f) + (validB ? lminB : 0.f);

    if (lane == 0) wl[wave] = wsum_loss;
    __syncthreads();
    if (tid == 0) {
        float s = 0.f;
        #pragma unroll
        for (int i = 0; i < 8; ++i) s += wl[i];   // fixed order: deterministic
        blocksums[b] = s;
    }
}

// ---------------- final mean ----------------
__global__ __launch_bounds__(256) void finish_kernel(
        const float* __restrict__ blocksums,
        float* __restrict__ out) {
    int tid = threadIdx.x;
    float s = 0.f;
    for (int i = tid; i < NBLK; i += 256) s += blocksums[i];
    __shared__ float sh[256];
    sh[tid] = s;
    __syncthreads();
    for (int off = 128; off > 0; off >>= 1) {
        if (tid < off) sh[tid] += sh[tid + off];
        __syncthreads();
    }
    if (tid == 0) out[0] = sh[0] / (float)NW;
}

extern "C" void kernel_launch(void* const* d_in, const int* in_sizes, int n_in,
                              void* d_out, int out_size, void* d_ws, size_t ws_size,
                              hipStream_t stream) {
    const float* data   = (const float*)d_in[0];
    const float* target = (const float*)d_in[1];
    float* blocksums = (float*)d_ws;

    loss_fused<<<NBLK, 512, 0, stream>>>(data, target, blocksums);
    finish_kernel<<<1, 256, 0, stream>>>(blocksums, (float*)d_out);
}